// Round 2
// baseline (445.623 us; speedup 1.0000x reference)
//
#include <hip/hip_runtime.h>

typedef unsigned short u16;
typedef __attribute__((ext_vector_type(8))) short s16x8;
typedef __attribute__((ext_vector_type(4))) short s16x4;
typedef __attribute__((ext_vector_type(4))) float f32x4;

__device__ __forceinline__ u16 f2bf(float f) {
    unsigned int u;
    __builtin_memcpy(&u, &f, 4);
    unsigned int r = u + 0x7FFFu + ((u >> 16) & 1u);   // RNE
    return (u16)(r >> 16);
}

__device__ __forceinline__ void gl_lds16(const u16* g, u16* l) {
    __builtin_amdgcn_global_load_lds(
        (const __attribute__((address_space(1))) unsigned int*)g,
        (__attribute__((address_space(3))) unsigned int*)l,
        16, 0, 0);
}

// ---------------------------------------------------------------------------
// Transpose f32 -> bf16: out[c][r] = bf16(in[r][c]). grid = (cols/64, rows/64)
// ---------------------------------------------------------------------------
__global__ __launch_bounds__(256) void k_transpose(const float* __restrict__ in,
                                                   u16* __restrict__ out,
                                                   int rows, int cols) {
    __shared__ float tile[64][65];
    int bx = blockIdx.x * 64, by = blockIdx.y * 64;
    int tx = threadIdx.x & 63, ty = threadIdx.x >> 6;
    for (int i = ty; i < 64; i += 4)
        tile[i][tx] = in[(size_t)(by + i) * cols + bx + tx];
    __syncthreads();
    for (int i = ty; i < 64; i += 4)
        out[(size_t)(bx + i) * rows + by + tx] = f2bf(tile[tx][i]);
}

// ---------------------------------------------------------------------------
// GEMM1: qkv[8192][768] = tokens[8192][4096] @ W_qkvT[768][4096]^T
// A-tile is gathered DIRECTLY from x (f32) with fused pixel-unshuffle +
// f32->bf16 convert (register path + ds_write). B staged via global_load_lds.
// tokens[b*1024+yy*32+xx][c0*64+r1*8+r2] = x[b][c0][yy*8+r1][xx*8+r2]
// Epilogue scatters into Q/K/V [b][h][n][d] (bf16).
// ---------------------------------------------------------------------------
__global__ __launch_bounds__(256) void k_gemm_qkv(const float* __restrict__ x,
                                                  const u16* __restrict__ Bt,
                                                  u16* __restrict__ Qo,
                                                  u16* __restrict__ Ko,
                                                  u16* __restrict__ Vo) {
    const int K = 4096;
    __shared__ u16 As[128 * 64];
    __shared__ u16 Bs[128 * 64];
    const int tid = threadIdx.x;
    const int wave = tid >> 6, lane = tid & 63;
    const int quad = lane >> 4, l15 = lane & 15;
    const int wm = wave >> 1, wn = wave & 1;
    const int tm = blockIdx.y * 128, tn = blockIdx.x * 128;

    f32x4 acc[4][4] = {};

    for (int k0 = 0; k0 < K; k0 += 64) {
        __syncthreads();
        // A: fused unshuffle gather, f32 -> bf16, ds_write 16B per slot
        for (int t = 0; t < 4; ++t) {
            int s = t * 256 + tid;               // slot in [0,1024)
            int m = tm + (s >> 3);
            int c = k0 + (s & 7) * 8;            // octet-aligned channel
            int b = m >> 10, n = m & 1023, yy = n >> 5, xx = n & 31;
            int c0 = c >> 6, r1 = (c >> 3) & 7;
            const float* src = x + ((size_t)((b * 64 + c0) * 256 + yy * 8 + r1)) * 256 + xx * 8;
            float4 f0 = *(const float4*)(src);
            float4 f1 = *(const float4*)(src + 4);
            s16x8 v;
            v[0] = (short)f2bf(f0.x); v[1] = (short)f2bf(f0.y);
            v[2] = (short)f2bf(f0.z); v[3] = (short)f2bf(f0.w);
            v[4] = (short)f2bf(f1.x); v[5] = (short)f2bf(f1.y);
            v[6] = (short)f2bf(f1.z); v[7] = (short)f2bf(f1.w);
            *(s16x8*)(As + s * 8) = v;
        }
        // B: async global->LDS, 16B per lane
        for (int t = 0; t < 4; ++t) {
            int c = wave * 256 + t * 64 + lane;
            int row = c >> 3, kc = c & 7;
            gl_lds16(Bt + (size_t)(tn + row) * K + k0 + kc * 8,
                     Bs + (wave * 256 + t * 64) * 8);
        }
        __syncthreads();
        for (int kk = 0; kk < 64; kk += 32) {
            s16x8 af[4], bf[4];
            for (int i = 0; i < 4; ++i)
                af[i] = *(const s16x8*)(As + (wm * 64 + i * 16 + l15) * 64 + kk + quad * 8);
            for (int j = 0; j < 4; ++j)
                bf[j] = *(const s16x8*)(Bs + (wn * 64 + j * 16 + l15) * 64 + kk + quad * 8);
            for (int i = 0; i < 4; ++i)
                for (int j = 0; j < 4; ++j)
                    acc[i][j] = __builtin_amdgcn_mfma_f32_16x16x32_bf16(af[i], bf[j], acc[i][j], 0, 0, 0);
        }
    }

    // epilogue: col = which*256 + h*64 + d ; Q/K/V layout [b*4+h][n][d] bf16
    for (int i = 0; i < 4; ++i) {
        int mb = tm + wm * 64 + i * 16 + quad * 4;
        for (int j = 0; j < 4; ++j) {
            int col = tn + wn * 64 + j * 16 + l15;
            int which = col >> 8, h = (col >> 6) & 3, d = col & 63;
            u16* dst = (which == 0) ? Qo : (which == 1) ? Ko : Vo;
            for (int r = 0; r < 4; ++r) {
                int m = mb + r;
                int b = m >> 10, n = m & 1023;
                dst[((size_t)((b * 4 + h) * 1024 + n)) * 64 + d] = f2bf(acc[i][j][r]);
            }
        }
    }
}

// ---------------------------------------------------------------------------
// Flash attention: grid (16 q-tiles, 32 bh). Block 256 = 4 waves, each wave
// owns 16 q-rows. Online softmax in fp32, P via per-wave LDS round-trip.
// ---------------------------------------------------------------------------
__global__ __launch_bounds__(256) void k_attn(const u16* __restrict__ Qb,
                                              const u16* __restrict__ Kb,
                                              const u16* __restrict__ Vb,
                                              u16* __restrict__ aout) {
    const int bh = blockIdx.y;
    const int q0 = blockIdx.x * 64;
    const int tid = threadIdx.x;
    const int wave = tid >> 6, lane = tid & 63;
    const int quad = lane >> 4, l15 = lane & 15;
    const size_t base = (size_t)bh * 1024 * 64;
    const float scale = 0.125f;

    __shared__ u16 Ks[64 * 64];
    __shared__ u16 Vts[64 * 68];     // V transposed [d][kv], pad 68
    __shared__ u16 Ps[4][16 * 64];   // per-wave P scratch

    // Q fragment (A-layout): lane holds Q[q0+wave*16+l15][quad*8+j (+32)]
    s16x8 aq0, aq1;
    {
        const u16* qp = Qb + base + (size_t)(q0 + wave * 16 + l15) * 64 + quad * 8;
        aq0 = *(const s16x8*)(qp);
        aq1 = *(const s16x8*)(qp + 32);
    }

    float m_i[4], l_i[4];
    f32x4 o[4] = {};
    for (int r = 0; r < 4; ++r) { m_i[r] = -1e30f; l_i[r] = 0.f; }

    for (int t = 0; t < 16; ++t) {
        __syncthreads();
        for (int e = 0; e < 2; ++e) {      // K tile [64][64]
            int s = e * 256 + tid;
            int row = s >> 3, off = (s & 7) * 8;
            *(s16x8*)(Ks + row * 64 + off) =
                *(const s16x8*)(Kb + base + (size_t)(t * 64 + row) * 64 + off);
        }
        for (int e = 0; e < 16; ++e) {     // Vts[d][kv] = V[t*64+kv][d]
            int s = e * 256 + tid;
            int kv = s >> 6, d = s & 63;
            Vts[d * 68 + kv] = Vb[base + (size_t)(t * 64 + kv) * 64 + d];
        }
        __syncthreads();

        // S = Q K^T (per wave: 16 q-rows x 64 kv-cols)
        f32x4 s4[4];
        for (int j = 0; j < 4; ++j) {
            const u16* kr = Ks + (j * 16 + l15) * 64 + quad * 8;
            s16x8 b0 = *(const s16x8*)(kr);
            s16x8 b1 = *(const s16x8*)(kr + 32);
            f32x4 c = {};
            c = __builtin_amdgcn_mfma_f32_16x16x32_bf16(aq0, b0, c, 0, 0, 0);
            c = __builtin_amdgcn_mfma_f32_16x16x32_bf16(aq1, b1, c, 0, 0, 0);
            s4[j] = c;
        }

        // online softmax; lane's rows are quad*4 + r
        for (int r = 0; r < 4; ++r) {
            float sv0 = s4[0][r] * scale, sv1 = s4[1][r] * scale;
            float sv2 = s4[2][r] * scale, sv3 = s4[3][r] * scale;
            float mt = fmaxf(fmaxf(sv0, sv1), fmaxf(sv2, sv3));
            for (int off = 1; off < 16; off <<= 1)
                mt = fmaxf(mt, __shfl_xor(mt, off, 64));
            float mn = fmaxf(m_i[r], mt);
            float alpha = __expf(m_i[r] - mn);
            m_i[r] = mn;
            float p0 = __expf(sv0 - mn), p1 = __expf(sv1 - mn);
            float p2 = __expf(sv2 - mn), p3 = __expf(sv3 - mn);
            u16* pw = Ps[wave] + (quad * 4 + r) * 64 + l15;
            pw[0]  = f2bf(p0);
            pw[16] = f2bf(p1);
            pw[32] = f2bf(p2);
            pw[48] = f2bf(p3);
            float rs = p0 + p1 + p2 + p3;
            for (int off = 1; off < 16; off <<= 1)
                rs += __shfl_xor(rs, off, 64);
            l_i[r] = l_i[r] * alpha + rs;
            for (int dt = 0; dt < 4; ++dt) o[dt][r] *= alpha;
        }

        // O += P @ V  (P in A-layout from LDS; V^T rows give B-layout)
        for (int kk = 0; kk < 64; kk += 32) {
            s16x8 pf = *(const s16x8*)(Ps[wave] + l15 * 64 + kk + quad * 8);
            for (int dt = 0; dt < 4; ++dt) {
                const u16* vr = Vts + (dt * 16 + l15) * 68 + kk + quad * 8;
                s16x4 v0 = *(const s16x4*)(vr);
                s16x4 v1 = *(const s16x4*)(vr + 4);
                s16x8 vf;
                vf[0] = v0[0]; vf[1] = v0[1]; vf[2] = v0[2]; vf[3] = v0[3];
                vf[4] = v1[0]; vf[5] = v1[1]; vf[6] = v1[2]; vf[7] = v1[3];
                o[dt] = __builtin_amdgcn_mfma_f32_16x16x32_bf16(pf, vf, o[dt], 0, 0, 0);
            }
        }
    }

    // write O/l -> aout[b*1024+q][h*64+d] (bf16)
    int b = bh >> 2, h = bh & 3;
    for (int dt = 0; dt < 4; ++dt)
        for (int r = 0; r < 4; ++r) {
            int qrow = q0 + wave * 16 + quad * 4 + r;
            float val = o[dt][r] / l_i[r];
            aout[((size_t)(b) * 1024 + qrow) * 256 + h * 64 + dt * 16 + l15] = f2bf(val);
        }
}

// ---------------------------------------------------------------------------
// GEMM2: y[8192][4096] = aout[8192][256] @ W_outT[4096][256]^T + bias
// Epilogue fuses bias + pixel-shuffle scatter into f32 out[8,64,256,256].
// ---------------------------------------------------------------------------
__global__ __launch_bounds__(256) void k_gemm_out(const u16* __restrict__ A,
                                                  const u16* __restrict__ Bt,
                                                  const float* __restrict__ bias,
                                                  float* __restrict__ out) {
    const int K = 256;
    __shared__ u16 As[128 * 64];
    __shared__ u16 Bs[128 * 64];
    const int tid = threadIdx.x;
    const int wave = tid >> 6, lane = tid & 63;
    const int quad = lane >> 4, l15 = lane & 15;
    const int wm = wave >> 1, wn = wave & 1;
    const int tm = blockIdx.y * 128, tn = blockIdx.x * 128;

    f32x4 acc[4][4] = {};

    for (int k0 = 0; k0 < K; k0 += 64) {
        __syncthreads();
        for (int t = 0; t < 4; ++t) {
            int c = wave * 256 + t * 64 + lane;
            int row = c >> 3, kc = c & 7;
            gl_lds16(A + (size_t)(tm + row) * K + k0 + kc * 8,
                     As + (wave * 256 + t * 64) * 8);
        }
        for (int t = 0; t < 4; ++t) {
            int c = wave * 256 + t * 64 + lane;
            int row = c >> 3, kc = c & 7;
            gl_lds16(Bt + (size_t)(tn + row) * K + k0 + kc * 8,
                     Bs + (wave * 256 + t * 64) * 8);
        }
        __syncthreads();
        for (int kk = 0; kk < 64; kk += 32) {
            s16x8 af[4], bf[4];
            for (int i = 0; i < 4; ++i)
                af[i] = *(const s16x8*)(As + (wm * 64 + i * 16 + l15) * 64 + kk + quad * 8);
            for (int j = 0; j < 4; ++j)
                bf[j] = *(const s16x8*)(Bs + (wn * 64 + j * 16 + l15) * 64 + kk + quad * 8);
            for (int i = 0; i < 4; ++i)
                for (int j = 0; j < 4; ++j)
                    acc[i][j] = __builtin_amdgcn_mfma_f32_16x16x32_bf16(af[i], bf[j], acc[i][j], 0, 0, 0);
        }
    }

    // epilogue: col -> (c0,r1,r2); row -> (b,yy,xx); pixel-shuffle scatter
    for (int i = 0; i < 4; ++i) {
        int mb = tm + wm * 64 + i * 16 + quad * 4;
        for (int j = 0; j < 4; ++j) {
            int col = tn + wn * 64 + j * 16 + l15;
            float bb = bias[col];
            int c0 = col >> 6, r1 = (col >> 3) & 7, r2 = col & 7;
            for (int r = 0; r < 4; ++r) {
                int m = mb + r;
                int b = m >> 10, n = m & 1023, yy = n >> 5, xx = n & 31;
                size_t oidx = ((size_t)((b * 64 + c0) * 256 + yy * 8 + r1)) * 256 + xx * 8 + r2;
                out[oidx] = acc[i][j][r] + bb;
            }
        }
    }
}

// ---------------------------------------------------------------------------
extern "C" void kernel_launch(void* const* d_in, const int* in_sizes, int n_in,
                              void* d_out, int out_size, void* d_ws, size_t ws_size,
                              hipStream_t stream) {
    (void)in_sizes; (void)n_in; (void)out_size; (void)ws_size;
    const float* x    = (const float*)d_in[0];
    const float* Wqkv = (const float*)d_in[1];   // [4096][768]
    const float* Wout = (const float*)d_in[2];   // [256][4096]
    const float* bout = (const float*)d_in[3];   // [4096]
    float* out = (float*)d_out;

    u16* ws    = (u16*)d_ws;
    u16* wqkvT = ws;                         // 768*4096   = 3,145,728
    u16* woutT = wqkvT + 3145728;            // 4096*256   = 1,048,576
    u16* Qb    = woutT + 1048576;            // 32*1024*64 = 2,097,152
    u16* Kb    = Qb + 2097152;
    u16* Vb    = Kb + 2097152;
    u16* aoutb = Vb + 2097152;               // 8192*256   = 2,097,152
    // total 12,582,912 u16 = 24 MiB

    k_transpose<<<dim3(12, 64), 256, 0, stream>>>(Wqkv, wqkvT, 4096, 768);
    k_transpose<<<dim3(64, 4), 256, 0, stream>>>(Wout, woutT, 256, 4096);
    k_gemm_qkv<<<dim3(6, 64), 256, 0, stream>>>(x, wqkvT, Qb, Kb, Vb);
    k_attn<<<dim3(16, 32), 256, 0, stream>>>(Qb, Kb, Vb, aoutb);
    k_gemm_out<<<dim3(32, 64), 256, 0, stream>>>(aoutb, woutT, bout, out);
}

// Round 3
// 428.497 us; speedup vs baseline: 1.0400x; 1.0400x over previous
//
#include <hip/hip_runtime.h>

typedef unsigned short u16;
typedef __attribute__((ext_vector_type(8))) short s16x8;
typedef __attribute__((ext_vector_type(4))) short s16x4;
typedef __attribute__((ext_vector_type(4))) float f32x4;

__device__ __forceinline__ u16 f2bf(float f) {
    unsigned int u;
    __builtin_memcpy(&u, &f, 4);
    unsigned int r = u + 0x7FFFu + ((u >> 16) & 1u);   // RNE
    return (u16)(r >> 16);
}

__device__ __forceinline__ void gl_lds16(const u16* g, u16* l) {
    __builtin_amdgcn_global_load_lds(
        (const __attribute__((address_space(1))) unsigned int*)g,
        (__attribute__((address_space(3))) unsigned int*)l,
        16, 0, 0);
}

// ---------------------------------------------------------------------------
// Pixel-unshuffle: x f32 [8,64,256,256] -> tokens bf16 [8192][4096]
// tokens[b*1024+yy*32+xx][c0*64+r1*8+r2] = x[b][c0][yy*8+r1][xx*8+r2]
// Thread: 128B contiguous read, 4 x 16B stores.
// ---------------------------------------------------------------------------
__global__ __launch_bounds__(256) void k_unshuffle(const float* __restrict__ x,
                                                   u16* __restrict__ tok) {
    int idx = blockIdx.x * 256 + threadIdx.x;     // [0, 2^20)
    int r1  = idx & 7;
    int xxg = (idx >> 3) & 7;                     // group of 4 xx
    int yy  = (idx >> 6) & 31;
    int c0  = (idx >> 11) & 63;
    int b   = idx >> 17;

    const float* src = x + ((size_t)((b * 64 + c0) * 256 + yy * 8 + r1)) * 256 + xxg * 32;
    int mbase = b * 1024 + yy * 32 + xxg * 4;
    int cbase = c0 * 64 + r1 * 8;
    for (int q = 0; q < 4; ++q) {
        float4 f0 = *(const float4*)(src + q * 8);
        float4 f1 = *(const float4*)(src + q * 8 + 4);
        s16x8 v;
        v[0] = (short)f2bf(f0.x); v[1] = (short)f2bf(f0.y);
        v[2] = (short)f2bf(f0.z); v[3] = (short)f2bf(f0.w);
        v[4] = (short)f2bf(f1.x); v[5] = (short)f2bf(f1.y);
        v[6] = (short)f2bf(f1.z); v[7] = (short)f2bf(f1.w);
        *(s16x8*)(tok + (size_t)(mbase + q) * 4096 + cbase) = v;
    }
}

// ---------------------------------------------------------------------------
// Transpose f32 -> bf16: out[c][r] = bf16(in[r][c]). grid = (cols/64, rows/64)
// ---------------------------------------------------------------------------
__global__ __launch_bounds__(256) void k_transpose(const float* __restrict__ in,
                                                   u16* __restrict__ out,
                                                   int rows, int cols) {
    __shared__ float tile[64][65];
    int bx = blockIdx.x * 64, by = blockIdx.y * 64;
    int tx = threadIdx.x & 63, ty = threadIdx.x >> 6;
    for (int i = ty; i < 64; i += 4)
        tile[i][tx] = in[(size_t)(by + i) * cols + bx + tx];
    __syncthreads();
    for (int i = ty; i < 64; i += 4)
        out[(size_t)(bx + i) * rows + by + tx] = f2bf(tile[tx][i]);
}

// ---------------------------------------------------------------------------
// GEMM1 (split-K=2): P[z][8192][768] = tokens[8192][4096(z-half)] @ WqkvT^T
// Pure m97 structure: both A and B staged via global_load_lds width-16.
// grid (6, 64, 2); f32 partials.
// ---------------------------------------------------------------------------
__global__ __launch_bounds__(256) void k_gemm_qkv(const u16* __restrict__ A,
                                                  const u16* __restrict__ Bt,
                                                  float* __restrict__ P) {
    const int K = 4096;
    __shared__ u16 As[128 * 64];
    __shared__ u16 Bs[128 * 64];
    const int tid = threadIdx.x;
    const int wave = tid >> 6, lane = tid & 63;
    const int quad = lane >> 4, l15 = lane & 15;
    const int wm = wave >> 1, wn = wave & 1;
    const int tm = blockIdx.y * 128, tn = blockIdx.x * 128;
    const int z = blockIdx.z;

    f32x4 acc[4][4] = {};

    for (int k0 = z * 2048; k0 < (z + 1) * 2048; k0 += 64) {
        __syncthreads();
        for (int t = 0; t < 4; ++t) {
            int c = wave * 256 + t * 64 + lane;
            int row = c >> 3, kc = c & 7;
            gl_lds16(A + (size_t)(tm + row) * K + k0 + kc * 8,
                     As + (wave * 256 + t * 64) * 8);
        }
        for (int t = 0; t < 4; ++t) {
            int c = wave * 256 + t * 64 + lane;
            int row = c >> 3, kc = c & 7;
            gl_lds16(Bt + (size_t)(tn + row) * K + k0 + kc * 8,
                     Bs + (wave * 256 + t * 64) * 8);
        }
        __syncthreads();
        for (int kk = 0; kk < 64; kk += 32) {
            s16x8 af[4], bf[4];
            for (int i = 0; i < 4; ++i)
                af[i] = *(const s16x8*)(As + (wm * 64 + i * 16 + l15) * 64 + kk + quad * 8);
            for (int j = 0; j < 4; ++j)
                bf[j] = *(const s16x8*)(Bs + (wn * 64 + j * 16 + l15) * 64 + kk + quad * 8);
            for (int i = 0; i < 4; ++i)
                for (int j = 0; j < 4; ++j)
                    acc[i][j] = __builtin_amdgcn_mfma_f32_16x16x32_bf16(af[i], bf[j], acc[i][j], 0, 0, 0);
        }
    }

    float* Pz = P + (size_t)z * 8192 * 768;
    for (int i = 0; i < 4; ++i) {
        int mb = tm + wm * 64 + i * 16 + quad * 4;
        for (int j = 0; j < 4; ++j) {
            int col = tn + wn * 64 + j * 16 + l15;
            for (int r = 0; r < 4; ++r)
                Pz[(size_t)(mb + r) * 768 + col] = acc[i][j][r];
        }
    }
}

// ---------------------------------------------------------------------------
// Split-K reduce + scatter into Q/K/V [b*4+h][n][d] bf16. grid (3, 8192).
// ---------------------------------------------------------------------------
__global__ __launch_bounds__(256) void k_qkv_reduce(const float* __restrict__ P,
                                                    u16* __restrict__ Qo,
                                                    u16* __restrict__ Ko,
                                                    u16* __restrict__ Vo) {
    int col = blockIdx.x * 256 + threadIdx.x;   // [0,768)
    int m   = blockIdx.y;                       // [0,8192)
    float v = P[(size_t)m * 768 + col] + P[(size_t)(8192 * 768) + (size_t)m * 768 + col];
    int which = col >> 8, h = (col >> 6) & 3, d = col & 63;
    int b = m >> 10, n = m & 1023;
    u16* dst = (which == 0) ? Qo : (which == 1) ? Ko : Vo;
    dst[((size_t)((b * 4 + h) * 1024 + n)) * 64 + d] = f2bf(v);
}

// ---------------------------------------------------------------------------
// Flash attention: grid (16 q-tiles, 32 bh). Block 256 = 4 waves, each wave
// owns 16 q-rows. Online softmax in fp32, P via per-wave LDS round-trip.
// ---------------------------------------------------------------------------
__global__ __launch_bounds__(256) void k_attn(const u16* __restrict__ Qb,
                                              const u16* __restrict__ Kb,
                                              const u16* __restrict__ Vb,
                                              u16* __restrict__ aout) {
    const int bh = blockIdx.y;
    const int q0 = blockIdx.x * 64;
    const int tid = threadIdx.x;
    const int wave = tid >> 6, lane = tid & 63;
    const int quad = lane >> 4, l15 = lane & 15;
    const size_t base = (size_t)bh * 1024 * 64;
    const float scale = 0.125f;

    __shared__ u16 Ks[64 * 64];
    __shared__ u16 Vts[64 * 68];     // V transposed [d][kv], pad 68
    __shared__ u16 Ps[4][16 * 64];   // per-wave P scratch

    s16x8 aq0, aq1;
    {
        const u16* qp = Qb + base + (size_t)(q0 + wave * 16 + l15) * 64 + quad * 8;
        aq0 = *(const s16x8*)(qp);
        aq1 = *(const s16x8*)(qp + 32);
    }

    float m_i[4], l_i[4];
    f32x4 o[4] = {};
    for (int r = 0; r < 4; ++r) { m_i[r] = -1e30f; l_i[r] = 0.f; }

    for (int t = 0; t < 16; ++t) {
        __syncthreads();
        for (int e = 0; e < 2; ++e) {      // K tile [64][64]
            int s = e * 256 + tid;
            int row = s >> 3, off = (s & 7) * 8;
            *(s16x8*)(Ks + row * 64 + off) =
                *(const s16x8*)(Kb + base + (size_t)(t * 64 + row) * 64 + off);
        }
        for (int e = 0; e < 16; ++e) {     // Vts[d][kv] = V[t*64+kv][d]
            int s = e * 256 + tid;
            int kv = s >> 6, d = s & 63;
            Vts[d * 68 + kv] = Vb[base + (size_t)(t * 64 + kv) * 64 + d];
        }
        __syncthreads();

        f32x4 s4[4];
        for (int j = 0; j < 4; ++j) {
            const u16* kr = Ks + (j * 16 + l15) * 64 + quad * 8;
            s16x8 b0 = *(const s16x8*)(kr);
            s16x8 b1 = *(const s16x8*)(kr + 32);
            f32x4 c = {};
            c = __builtin_amdgcn_mfma_f32_16x16x32_bf16(aq0, b0, c, 0, 0, 0);
            c = __builtin_amdgcn_mfma_f32_16x16x32_bf16(aq1, b1, c, 0, 0, 0);
            s4[j] = c;
        }

        for (int r = 0; r < 4; ++r) {
            float sv0 = s4[0][r] * scale, sv1 = s4[1][r] * scale;
            float sv2 = s4[2][r] * scale, sv3 = s4[3][r] * scale;
            float mt = fmaxf(fmaxf(sv0, sv1), fmaxf(sv2, sv3));
            for (int off = 1; off < 16; off <<= 1)
                mt = fmaxf(mt, __shfl_xor(mt, off, 64));
            float mn = fmaxf(m_i[r], mt);
            float alpha = __expf(m_i[r] - mn);
            m_i[r] = mn;
            float p0 = __expf(sv0 - mn), p1 = __expf(sv1 - mn);
            float p2 = __expf(sv2 - mn), p3 = __expf(sv3 - mn);
            u16* pw = Ps[wave] + (quad * 4 + r) * 64 + l15;
            pw[0]  = f2bf(p0);
            pw[16] = f2bf(p1);
            pw[32] = f2bf(p2);
            pw[48] = f2bf(p3);
            float rs = p0 + p1 + p2 + p3;
            for (int off = 1; off < 16; off <<= 1)
                rs += __shfl_xor(rs, off, 64);
            l_i[r] = l_i[r] * alpha + rs;
            for (int dt = 0; dt < 4; ++dt) o[dt][r] *= alpha;
        }

        for (int kk = 0; kk < 64; kk += 32) {
            s16x8 pf = *(const s16x8*)(Ps[wave] + l15 * 64 + kk + quad * 8);
            for (int dt = 0; dt < 4; ++dt) {
                const u16* vr = Vts + (dt * 16 + l15) * 68 + kk + quad * 8;
                s16x4 v0 = *(const s16x4*)(vr);
                s16x4 v1 = *(const s16x4*)(vr + 4);
                s16x8 vf;
                vf[0] = v0[0]; vf[1] = v0[1]; vf[2] = v0[2]; vf[3] = v0[3];
                vf[4] = v1[0]; vf[5] = v1[1]; vf[6] = v1[2]; vf[7] = v1[3];
                o[dt] = __builtin_amdgcn_mfma_f32_16x16x32_bf16(pf, vf, o[dt], 0, 0, 0);
            }
        }
    }

    int b = bh >> 2, h = bh & 3;
    for (int dt = 0; dt < 4; ++dt)
        for (int r = 0; r < 4; ++r) {
            int qrow = q0 + wave * 16 + quad * 4 + r;
            float val = o[dt][r] / l_i[r];
            aout[((size_t)(b) * 1024 + qrow) * 256 + h * 64 + dt * 16 + l15] = f2bf(val);
        }
}

// ---------------------------------------------------------------------------
// GEMM2: y[8192][4096] = aout[8192][256] @ W_outT[4096][256]^T + bias
// Epilogue fuses bias + pixel-shuffle scatter into f32 out[8,64,256,256].
// ---------------------------------------------------------------------------
__global__ __launch_bounds__(256) void k_gemm_out(const u16* __restrict__ A,
                                                  const u16* __restrict__ Bt,
                                                  const float* __restrict__ bias,
                                                  float* __restrict__ out) {
    const int K = 256;
    __shared__ u16 As[128 * 64];
    __shared__ u16 Bs[128 * 64];
    const int tid = threadIdx.x;
    const int wave = tid >> 6, lane = tid & 63;
    const int quad = lane >> 4, l15 = lane & 15;
    const int wm = wave >> 1, wn = wave & 1;
    const int tm = blockIdx.y * 128, tn = blockIdx.x * 128;

    f32x4 acc[4][4] = {};

    for (int k0 = 0; k0 < K; k0 += 64) {
        __syncthreads();
        for (int t = 0; t < 4; ++t) {
            int c = wave * 256 + t * 64 + lane;
            int row = c >> 3, kc = c & 7;
            gl_lds16(A + (size_t)(tm + row) * K + k0 + kc * 8,
                     As + (wave * 256 + t * 64) * 8);
        }
        for (int t = 0; t < 4; ++t) {
            int c = wave * 256 + t * 64 + lane;
            int row = c >> 3, kc = c & 7;
            gl_lds16(Bt + (size_t)(tn + row) * K + k0 + kc * 8,
                     Bs + (wave * 256 + t * 64) * 8);
        }
        __syncthreads();
        for (int kk = 0; kk < 64; kk += 32) {
            s16x8 af[4], bf[4];
            for (int i = 0; i < 4; ++i)
                af[i] = *(const s16x8*)(As + (wm * 64 + i * 16 + l15) * 64 + kk + quad * 8);
            for (int j = 0; j < 4; ++j)
                bf[j] = *(const s16x8*)(Bs + (wn * 64 + j * 16 + l15) * 64 + kk + quad * 8);
            for (int i = 0; i < 4; ++i)
                for (int j = 0; j < 4; ++j)
                    acc[i][j] = __builtin_amdgcn_mfma_f32_16x16x32_bf16(af[i], bf[j], acc[i][j], 0, 0, 0);
        }
    }

    for (int i = 0; i < 4; ++i) {
        int mb = tm + wm * 64 + i * 16 + quad * 4;
        for (int j = 0; j < 4; ++j) {
            int col = tn + wn * 64 + j * 16 + l15;
            float bb = bias[col];
            int c0 = col >> 6, r1 = (col >> 3) & 7, r2 = col & 7;
            for (int r = 0; r < 4; ++r) {
                int m = mb + r;
                int b = m >> 10, n = m & 1023, yy = n >> 5, xx = n & 31;
                size_t oidx = ((size_t)((b * 64 + c0) * 256 + yy * 8 + r1)) * 256 + xx * 8 + r2;
                out[oidx] = acc[i][j][r] + bb;
            }
        }
    }
}

// ---------------------------------------------------------------------------
extern "C" void kernel_launch(void* const* d_in, const int* in_sizes, int n_in,
                              void* d_out, int out_size, void* d_ws, size_t ws_size,
                              hipStream_t stream) {
    (void)in_sizes; (void)n_in; (void)out_size; (void)ws_size;
    const float* x    = (const float*)d_in[0];
    const float* Wqkv = (const float*)d_in[1];   // [4096][768]
    const float* Wout = (const float*)d_in[2];   // [256][4096]
    const float* bout = (const float*)d_in[3];   // [4096]
    float* out = (float*)d_out;

    u16* ws     = (u16*)d_ws;
    u16* tokens = ws;                        // 8192*4096      = 33,554,432 u16
    u16* wqkvT  = tokens + 33554432;         // 768*4096       =  3,145,728
    u16* woutT  = wqkvT + 3145728;           // 4096*256       =  1,048,576
    u16* Qb     = woutT + 1048576;           // 32*1024*64     =  2,097,152
    u16* Kb     = Qb + 2097152;
    u16* Vb     = Kb + 2097152;
    u16* aoutb  = Vb + 2097152;              // 8192*256       =  2,097,152
    float* Pp   = (float*)(aoutb + 2097152); // 2*8192*768 f32 = 50.3 MB
    // total ~143 MB

    k_unshuffle<<<4096, 256, 0, stream>>>(x, tokens);
    k_transpose<<<dim3(12, 64), 256, 0, stream>>>(Wqkv, wqkvT, 4096, 768);
    k_transpose<<<dim3(64, 4), 256, 0, stream>>>(Wout, woutT, 256, 4096);
    k_gemm_qkv<<<dim3(6, 64, 2), 256, 0, stream>>>(tokens, wqkvT, Pp);
    k_qkv_reduce<<<dim3(3, 8192), 256, 0, stream>>>(Pp, Qb, Kb, Vb);
    k_attn<<<dim3(16, 32), 256, 0, stream>>>(Qb, Kb, Vb, aoutb);
    k_gemm_out<<<dim3(32, 64), 256, 0, stream>>>(aoutb, woutT, bout, out);
}

// Round 4
// 422.138 us; speedup vs baseline: 1.0556x; 1.0151x over previous
//
#include <hip/hip_runtime.h>

typedef unsigned short u16;
typedef __attribute__((ext_vector_type(8))) short s16x8;
typedef __attribute__((ext_vector_type(4))) short s16x4;
typedef __attribute__((ext_vector_type(4))) float f32x4;

__device__ __forceinline__ u16 f2bf(float f) {
    unsigned int u;
    __builtin_memcpy(&u, &f, 4);
    unsigned int r = u + 0x7FFFu + ((u >> 16) & 1u);   // RNE
    return (u16)(r >> 16);
}

__device__ __forceinline__ void gl_lds16(const u16* g, u16* l) {
    __builtin_amdgcn_global_load_lds(
        (const __attribute__((address_space(1))) unsigned int*)g,
        (__attribute__((address_space(3))) unsigned int*)l,
        16, 0, 0);
}

// ---------------------------------------------------------------------------
// Pixel-unshuffle: x f32 [8,64,256,256] -> tokens bf16 [8192][4096]
// ---------------------------------------------------------------------------
__global__ __launch_bounds__(256) void k_unshuffle(const float* __restrict__ x,
                                                   u16* __restrict__ tok) {
    int idx = blockIdx.x * 256 + threadIdx.x;     // [0, 2^20)
    int r1  = idx & 7;
    int xxg = (idx >> 3) & 7;
    int yy  = (idx >> 6) & 31;
    int c0  = (idx >> 11) & 63;
    int b   = idx >> 17;

    const float* src = x + ((size_t)((b * 64 + c0) * 256 + yy * 8 + r1)) * 256 + xxg * 32;
    int mbase = b * 1024 + yy * 32 + xxg * 4;
    int cbase = c0 * 64 + r1 * 8;
    for (int q = 0; q < 4; ++q) {
        float4 f0 = *(const float4*)(src + q * 8);
        float4 f1 = *(const float4*)(src + q * 8 + 4);
        s16x8 v;
        v[0] = (short)f2bf(f0.x); v[1] = (short)f2bf(f0.y);
        v[2] = (short)f2bf(f0.z); v[3] = (short)f2bf(f0.w);
        v[4] = (short)f2bf(f1.x); v[5] = (short)f2bf(f1.y);
        v[6] = (short)f2bf(f1.z); v[7] = (short)f2bf(f1.w);
        *(s16x8*)(tok + (size_t)(mbase + q) * 4096 + cbase) = v;
    }
}

// ---------------------------------------------------------------------------
// Transpose f32 -> bf16: out[c][r] = bf16(in[r][c]). grid = (cols/64, rows/64)
// ---------------------------------------------------------------------------
__global__ __launch_bounds__(256) void k_transpose(const float* __restrict__ in,
                                                   u16* __restrict__ out,
                                                   int rows, int cols) {
    __shared__ float tile[64][65];
    int bx = blockIdx.x * 64, by = blockIdx.y * 64;
    int tx = threadIdx.x & 63, ty = threadIdx.x >> 6;
    for (int i = ty; i < 64; i += 4)
        tile[i][tx] = in[(size_t)(by + i) * cols + bx + tx];
    __syncthreads();
    for (int i = ty; i < 64; i += 4)
        out[(size_t)(bx + i) * rows + by + tx] = f2bf(tile[tx][i]);
}

// ---------------------------------------------------------------------------
// GEMM1 (split-K=2): P[z][8192][768] = tokens @ WqkvT^T.  m97 structure.
// ---------------------------------------------------------------------------
__global__ __launch_bounds__(256) void k_gemm_qkv(const u16* __restrict__ A,
                                                  const u16* __restrict__ Bt,
                                                  float* __restrict__ P) {
    const int K = 4096;
    __shared__ u16 As[128 * 64];
    __shared__ u16 Bs[128 * 64];
    const int tid = threadIdx.x;
    const int wave = tid >> 6, lane = tid & 63;
    const int quad = lane >> 4, l15 = lane & 15;
    const int wm = wave >> 1, wn = wave & 1;
    const int tm = blockIdx.y * 128, tn = blockIdx.x * 128;
    const int z = blockIdx.z;

    f32x4 acc[4][4] = {};

    for (int k0 = z * 2048; k0 < (z + 1) * 2048; k0 += 64) {
        __syncthreads();
        for (int t = 0; t < 4; ++t) {
            int c = wave * 256 + t * 64 + lane;
            int row = c >> 3, kc = c & 7;
            gl_lds16(A + (size_t)(tm + row) * K + k0 + kc * 8,
                     As + (wave * 256 + t * 64) * 8);
        }
        for (int t = 0; t < 4; ++t) {
            int c = wave * 256 + t * 64 + lane;
            int row = c >> 3, kc = c & 7;
            gl_lds16(Bt + (size_t)(tn + row) * K + k0 + kc * 8,
                     Bs + (wave * 256 + t * 64) * 8);
        }
        __syncthreads();
        for (int kk = 0; kk < 64; kk += 32) {
            s16x8 af[4], bf[4];
            for (int i = 0; i < 4; ++i)
                af[i] = *(const s16x8*)(As + (wm * 64 + i * 16 + l15) * 64 + kk + quad * 8);
            for (int j = 0; j < 4; ++j)
                bf[j] = *(const s16x8*)(Bs + (wn * 64 + j * 16 + l15) * 64 + kk + quad * 8);
            for (int i = 0; i < 4; ++i)
                for (int j = 0; j < 4; ++j)
                    acc[i][j] = __builtin_amdgcn_mfma_f32_16x16x32_bf16(af[i], bf[j], acc[i][j], 0, 0, 0);
        }
    }

    float* Pz = P + (size_t)z * 8192 * 768;
    for (int i = 0; i < 4; ++i) {
        int mb = tm + wm * 64 + i * 16 + quad * 4;
        for (int j = 0; j < 4; ++j) {
            int col = tn + wn * 64 + j * 16 + l15;
            for (int r = 0; r < 4; ++r)
                Pz[(size_t)(mb + r) * 768 + col] = acc[i][j][r];
        }
    }
}

// ---------------------------------------------------------------------------
// Split-K reduce + scatter. Q,K -> [bh][n][d]; V -> TRANSPOSED Vt[bh][d][n]
// (64x65-padded LDS tile transpose; both global sides coalesced).
// grid (12, 128), block 256.
// ---------------------------------------------------------------------------
__global__ __launch_bounds__(256) void k_qkv_reduce(const float* __restrict__ P,
                                                    u16* __restrict__ Qo,
                                                    u16* __restrict__ Ko,
                                                    u16* __restrict__ Vt) {
    __shared__ u16 tile[64][65];
    const int tid = threadIdx.x;
    const int ct = blockIdx.x, mt = blockIdx.y;
    const int c_l = tid & 63;
    const int col = ct * 64 + c_l;
    const int mbase = mt * 64;
    const float* P1 = P + (size_t)8192 * 768;

    if (ct < 8) {                       // Q (ct<4) / K (ct>=4), direct store
        int which = col >> 8;
        int h = (col >> 6) & 3, d = col & 63;
        u16* dst = (which == 0) ? Qo : Ko;
        for (int k = 0; k < 16; ++k) {
            int m = mbase + (tid >> 6) + k * 4;
            float v = P[(size_t)m * 768 + col] + P1[(size_t)m * 768 + col];
            int b = m >> 10, n = m & 1023;
            dst[((size_t)((b * 4 + h) * 1024 + n)) * 64 + d] = f2bf(v);
        }
    } else {                            // V: transpose to Vt[bh][d][n]
        int h = ct - 8;
        int b = mbase >> 10;
        int nbase = mbase & 1023;
        for (int k = 0; k < 16; ++k) {
            int ml = (tid >> 6) + k * 4;
            int m = mbase + ml;
            float v = P[(size_t)m * 768 + col] + P1[(size_t)m * 768 + col];
            tile[ml][c_l] = f2bf(v);
        }
        __syncthreads();
        for (int k = 0; k < 16; ++k) {
            int d = (tid >> 6) + k * 4;
            Vt[((size_t)((b * 4 + h) * 64 + d)) * 1024 + nbase + c_l] = tile[c_l][d];
        }
    }
}

// ---------------------------------------------------------------------------
// Flash attention. K tile: flat 8KB contiguous -> global_load_lds width16.
// V pre-transposed in global (Vt[bh][d][n]) -> vector load + ds_write_b128
// into padded Vts[64][68]. grid (16, 32), block 256.
// ---------------------------------------------------------------------------
__global__ __launch_bounds__(256) void k_attn(const u16* __restrict__ Qb,
                                              const u16* __restrict__ Kb,
                                              const u16* __restrict__ Vt,
                                              u16* __restrict__ aout) {
    const int bh = blockIdx.y;
    const int q0 = blockIdx.x * 64;
    const int tid = threadIdx.x;
    const int wave = tid >> 6, lane = tid & 63;
    const int quad = lane >> 4, l15 = lane & 15;
    const size_t base = (size_t)bh * 1024 * 64;
    const float scale = 0.125f;

    __shared__ u16 Ks[64 * 64];
    __shared__ u16 Vts[64 * 68];     // [d][kv], pad 68
    __shared__ u16 Ps[4][16 * 64];   // per-wave P scratch

    s16x8 aq0, aq1;
    {
        const u16* qp = Qb + base + (size_t)(q0 + wave * 16 + l15) * 64 + quad * 8;
        aq0 = *(const s16x8*)(qp);
        aq1 = *(const s16x8*)(qp + 32);
    }

    float m_i[4], l_i[4];
    f32x4 o[4] = {};
    for (int r = 0; r < 4; ++r) { m_i[r] = -1e30f; l_i[r] = 0.f; }

    const int vrow = tid >> 2, vpart = tid & 3;

    for (int t = 0; t < 16; ++t) {
        __syncthreads();
        // K tile: 4096 contiguous u16 -> LDS, async 16B per lane
        for (int e = 0; e < 2; ++e) {
            int s = e * 256 + tid;
            gl_lds16(Kb + base + (size_t)t * 4096 + s * 8, Ks + s * 8);
        }
        // V tile from Vt: row vrow, 16 u16 per thread, ds_write_b128 x2
        {
            const u16* src = Vt + base + (size_t)vrow * 1024 + t * 64 + vpart * 16;
            s16x8 a = *(const s16x8*)(src);
            s16x8 b2 = *(const s16x8*)(src + 8);
            *(s16x8*)(Vts + vrow * 68 + vpart * 16) = a;
            *(s16x8*)(Vts + vrow * 68 + vpart * 16 + 8) = b2;
        }
        __syncthreads();

        // S = Q K^T (wave: 16 q-rows x 64 kv-cols)
        f32x4 s4[4];
        for (int j = 0; j < 4; ++j) {
            const u16* kr = Ks + (j * 16 + l15) * 64 + quad * 8;
            s16x8 b0 = *(const s16x8*)(kr);
            s16x8 b1 = *(const s16x8*)(kr + 32);
            f32x4 c = {};
            c = __builtin_amdgcn_mfma_f32_16x16x32_bf16(aq0, b0, c, 0, 0, 0);
            c = __builtin_amdgcn_mfma_f32_16x16x32_bf16(aq1, b1, c, 0, 0, 0);
            s4[j] = c;
        }

        // online softmax; lane's rows are quad*4 + r
        for (int r = 0; r < 4; ++r) {
            float sv0 = s4[0][r] * scale, sv1 = s4[1][r] * scale;
            float sv2 = s4[2][r] * scale, sv3 = s4[3][r] * scale;
            float mt = fmaxf(fmaxf(sv0, sv1), fmaxf(sv2, sv3));
            for (int off = 1; off < 16; off <<= 1)
                mt = fmaxf(mt, __shfl_xor(mt, off, 64));
            float mn = fmaxf(m_i[r], mt);
            float alpha = __expf(m_i[r] - mn);
            m_i[r] = mn;
            float p0 = __expf(sv0 - mn), p1 = __expf(sv1 - mn);
            float p2 = __expf(sv2 - mn), p3 = __expf(sv3 - mn);
            u16* pw = Ps[wave] + (quad * 4 + r) * 64 + l15;
            pw[0]  = f2bf(p0);
            pw[16] = f2bf(p1);
            pw[32] = f2bf(p2);
            pw[48] = f2bf(p3);
            float rs = p0 + p1 + p2 + p3;
            for (int off = 1; off < 16; off <<= 1)
                rs += __shfl_xor(rs, off, 64);
            l_i[r] = l_i[r] * alpha + rs;
            for (int dt = 0; dt < 4; ++dt) o[dt][r] *= alpha;
        }

        // O += P @ V
        for (int kk = 0; kk < 64; kk += 32) {
            s16x8 pf = *(const s16x8*)(Ps[wave] + l15 * 64 + kk + quad * 8);
            for (int dt = 0; dt < 4; ++dt) {
                const u16* vr = Vts + (dt * 16 + l15) * 68 + kk + quad * 8;
                s16x4 v0 = *(const s16x4*)(vr);
                s16x4 v1 = *(const s16x4*)(vr + 4);
                s16x8 vf;
                vf[0] = v0[0]; vf[1] = v0[1]; vf[2] = v0[2]; vf[3] = v0[3];
                vf[4] = v1[0]; vf[5] = v1[1]; vf[6] = v1[2]; vf[7] = v1[3];
                o[dt] = __builtin_amdgcn_mfma_f32_16x16x32_bf16(pf, vf, o[dt], 0, 0, 0);
            }
        }
    }

    int b = bh >> 2, h = bh & 3;
    float rl[4];
    for (int r = 0; r < 4; ++r) rl[r] = 1.0f / l_i[r];
    for (int dt = 0; dt < 4; ++dt)
        for (int r = 0; r < 4; ++r) {
            int qrow = q0 + wave * 16 + quad * 4 + r;
            aout[((size_t)(b) * 1024 + qrow) * 256 + h * 64 + dt * 16 + l15] =
                f2bf(o[dt][r] * rl[r]);
        }
}

// ---------------------------------------------------------------------------
// GEMM2: y[8192][4096] = aout[8192][256] @ W_outT^T + bias, fused shuffle.
// ---------------------------------------------------------------------------
__global__ __launch_bounds__(256) void k_gemm_out(const u16* __restrict__ A,
                                                  const u16* __restrict__ Bt,
                                                  const float* __restrict__ bias,
                                                  float* __restrict__ out) {
    const int K = 256;
    __shared__ u16 As[128 * 64];
    __shared__ u16 Bs[128 * 64];
    const int tid = threadIdx.x;
    const int wave = tid >> 6, lane = tid & 63;
    const int quad = lane >> 4, l15 = lane & 15;
    const int wm = wave >> 1, wn = wave & 1;
    const int tm = blockIdx.y * 128, tn = blockIdx.x * 128;

    f32x4 acc[4][4] = {};

    for (int k0 = 0; k0 < K; k0 += 64) {
        __syncthreads();
        for (int t = 0; t < 4; ++t) {
            int c = wave * 256 + t * 64 + lane;
            int row = c >> 3, kc = c & 7;
            gl_lds16(A + (size_t)(tm + row) * K + k0 + kc * 8,
                     As + (wave * 256 + t * 64) * 8);
        }
        for (int t = 0; t < 4; ++t) {
            int c = wave * 256 + t * 64 + lane;
            int row = c >> 3, kc = c & 7;
            gl_lds16(Bt + (size_t)(tn + row) * K + k0 + kc * 8,
                     Bs + (wave * 256 + t * 64) * 8);
        }
        __syncthreads();
        for (int kk = 0; kk < 64; kk += 32) {
            s16x8 af[4], bf[4];
            for (int i = 0; i < 4; ++i)
                af[i] = *(const s16x8*)(As + (wm * 64 + i * 16 + l15) * 64 + kk + quad * 8);
            for (int j = 0; j < 4; ++j)
                bf[j] = *(const s16x8*)(Bs + (wn * 64 + j * 16 + l15) * 64 + kk + quad * 8);
            for (int i = 0; i < 4; ++i)
                for (int j = 0; j < 4; ++j)
                    acc[i][j] = __builtin_amdgcn_mfma_f32_16x16x32_bf16(af[i], bf[j], acc[i][j], 0, 0, 0);
        }
    }

    for (int i = 0; i < 4; ++i) {
        int mb = tm + wm * 64 + i * 16 + quad * 4;
        for (int j = 0; j < 4; ++j) {
            int col = tn + wn * 64 + j * 16 + l15;
            float bb = bias[col];
            int c0 = col >> 6, r1 = (col >> 3) & 7, r2 = col & 7;
            for (int r = 0; r < 4; ++r) {
                int m = mb + r;
                int b = m >> 10, n = m & 1023, yy = n >> 5, xx = n & 31;
                size_t oidx = ((size_t)((b * 64 + c0) * 256 + yy * 8 + r1)) * 256 + xx * 8 + r2;
                out[oidx] = acc[i][j][r] + bb;
            }
        }
    }
}

// ---------------------------------------------------------------------------
extern "C" void kernel_launch(void* const* d_in, const int* in_sizes, int n_in,
                              void* d_out, int out_size, void* d_ws, size_t ws_size,
                              hipStream_t stream) {
    (void)in_sizes; (void)n_in; (void)out_size; (void)ws_size;
    const float* x    = (const float*)d_in[0];
    const float* Wqkv = (const float*)d_in[1];   // [4096][768]
    const float* Wout = (const float*)d_in[2];   // [256][4096]
    const float* bout = (const float*)d_in[3];   // [4096]
    float* out = (float*)d_out;

    u16* ws     = (u16*)d_ws;
    u16* tokens = ws;                        // 8192*4096
    u16* wqkvT  = tokens + 33554432;         // 768*4096
    u16* woutT  = wqkvT + 3145728;           // 4096*256
    u16* Qb     = woutT + 1048576;           // 32*1024*64
    u16* Kb     = Qb + 2097152;
    u16* Vtb    = Kb + 2097152;              // V transposed [bh][d][n]
    u16* aoutb  = Vtb + 2097152;             // 8192*256
    float* Pp   = (float*)(aoutb + 2097152); // 2*8192*768 f32

    k_unshuffle<<<4096, 256, 0, stream>>>(x, tokens);
    k_transpose<<<dim3(12, 64), 256, 0, stream>>>(Wqkv, wqkvT, 4096, 768);
    k_transpose<<<dim3(64, 4), 256, 0, stream>>>(Wout, woutT, 256, 4096);
    k_gemm_qkv<<<dim3(6, 64, 2), 256, 0, stream>>>(tokens, wqkvT, Pp);
    k_qkv_reduce<<<dim3(12, 128), 256, 0, stream>>>(Pp, Qb, Kb, Vtb);
    k_attn<<<dim3(16, 32), 256, 0, stream>>>(Qb, Kb, Vtb, aoutb);
    k_gemm_out<<<dim3(32, 64), 256, 0, stream>>>(aoutb, woutT, bout, out);
}